// Round 13
// baseline (31.633 us; speedup 1.0000x reference)
//
#include <hip/hip_runtime.h>
#include <hip/hip_bf16.h>
#include <math.h>

#define NNODES   100000
#define S        8192
#define D        8
#define EPSF     1e-6f
#define LOG2E    1.442695040888963f
#define EPS_S    (LOG2E * EPSF)
#define NT2      256        // 8192/32 tiles per dim

// ws byte offsets
#define ZHL_OFF  0          // 8192 rows x 16 ushort (hi[8]|lo[8]) = 262144 B
#define U_OFF    262144     // 8192 f32
#define V_OFF    294912     // 8192 f32
#define ZB_OFF   327680     // 100000 rows x 8 bf16 = 1.6 MB
#define BK_OFF   1928192    // bucket region
// bucket region layout (128-B stride each):
//   dbuck[64] doubles @ +0 ; sbuck[16] @ +64*128 ; cbuck[80] @ +80*128 ; gdone @ +160*128

#define NSBLK    256        // sparse blocks
#define NDBLK    1024       // dense blocks = 128 row-pairs x 8
#define NWPP     32         // waves per row-pair
#define CH       6          // dense tile chunk (register-batched loads)

typedef __attribute__((ext_vector_type(8)))  short short8_t;
typedef __attribute__((ext_vector_type(16))) float f32x16;

__device__ __forceinline__ float block_reduce_f(float v, float* sm) {
    #pragma unroll
    for (int off = 32; off > 0; off >>= 1) v += __shfl_down(v, off, 64);
    int lane = threadIdx.x & 63, wid = threadIdx.x >> 6;
    if (lane == 0) sm[wid] = v;
    __syncthreads();
    float s = 0.f;
    if (threadIdx.x == 0) {
        for (int w = 0; w < 4; ++w) s += sm[w];
    }
    return s;
}

// ---- kernel 1: sample-gather (prescaled hi/lo split) + full-Z bf16 copy ----
__global__ __launch_bounds__(256) void gather_kernel(const float* __restrict__ Z,
                                                     const int* __restrict__ idx,
                                                     ushort* __restrict__ zhl,
                                                     float* __restrict__ u,
                                                     float* __restrict__ v,
                                                     ushort* __restrict__ zb16,
                                                     char* __restrict__ buckets) {
    int gid = blockIdx.x * 256 + threadIdx.x;

    if (blockIdx.x == 0 && threadIdx.x < 161) {
        *(double*)(buckets + threadIdx.x * 128) = 0.0;
    }

    if (gid < S) {
        int n = idx[gid];
        const float4* zp = (const float4*)(Z + (size_t)n * D);
        float4 a = zp[0], b = zp[1];
        float z[8] = { a.x, a.y, a.z, a.w, b.x, b.y, b.z, b.w };
        float ss = 0.f;
        short8_t h, l;
        #pragma unroll
        for (int k = 0; k < 8; ++k) {
            float zs = LOG2E * z[k];
            ss = fmaf(zs, zs, ss);
            __hip_bfloat16 hb = __float2bfloat16(zs);
            float hf = __bfloat162float(hb);
            __hip_bfloat16 lb = __float2bfloat16(zs - hf);
            h[k] = (short)__builtin_bit_cast(unsigned short, hb);
            l[k] = (short)__builtin_bit_cast(unsigned short, lb);
        }
        *(short8_t*)(zhl + (size_t)gid * 16)     = h;
        *(short8_t*)(zhl + (size_t)gid * 16 + 8) = l;
        u[gid] = ss + 8.f * EPS_S * EPS_S;
        v[gid] = ss;
    }

    if (gid < NNODES) {
        const float4* zp = (const float4*)(Z + (size_t)gid * D);
        float4 a = zp[0], b = zp[1];
        float z[8] = { a.x, a.y, a.z, a.w, b.x, b.y, b.z, b.w };
        short8_t o;
        #pragma unroll
        for (int k = 0; k < 8; ++k) {
            __hip_bfloat16 bb = __float2bfloat16(z[k]);
            o[k] = (short)__builtin_bit_cast(unsigned short, bb);
        }
        *(short8_t*)(zb16 + (size_t)gid * 8) = o;
    }
}

// bf16 row (uint4) -> 8 f32
#define UNPACK8(u4, f)                                        \
    f[0] = __uint_as_float(u4.x << 16);                       \
    f[1] = __uint_as_float(u4.x & 0xffff0000u);               \
    f[2] = __uint_as_float(u4.y << 16);                       \
    f[3] = __uint_as_float(u4.y & 0xffff0000u);               \
    f[4] = __uint_as_float(u4.z << 16);                       \
    f[5] = __uint_as_float(u4.z & 0xffff0000u);               \
    f[6] = __uint_as_float(u4.w << 16);                       \
    f[7] = __uint_as_float(u4.w & 0xffff0000u);

// 8 edges: issue all 16 row-gathers, then compute.
__device__ __forceinline__ float edge_dist8(const uint4* __restrict__ zb,
                                            int4 ia0, int4 ia1, int4 ib0, int4 ib1) {
    int aidx[8] = { ia0.x, ia0.y, ia0.z, ia0.w, ia1.x, ia1.y, ia1.z, ia1.w };
    int bidx[8] = { ib0.x, ib0.y, ib0.z, ib0.w, ib1.x, ib1.y, ib1.z, ib1.w };
    uint4 ua[8], ub[8];
    #pragma unroll
    for (int q = 0; q < 8; ++q) { ua[q] = zb[aidx[q]]; ub[q] = zb[bidx[q]]; }
    float acc = 0.f;
    #pragma unroll
    for (int q = 0; q < 8; ++q) {
        float fa[8], fb[8];
        UNPACK8(ua[q], fa);
        UNPACK8(ub[q], fb);
        float s2 = 0.f;
        #pragma unroll
        for (int k = 0; k < 8; ++k) {
            float d = fa[k] - fb[k] + EPSF;
            s2 = fmaf(d, d, s2);
        }
        acc += __builtin_amdgcn_sqrtf(s2);
    }
    return acc;
}

// Sweep `cnt` consecutive 32x32 j-tiles from tj0 for fixed i-tile ti, in
// CH-tile chunks: issue all chunk loads (independent), wait once, then
// compute CH tiles from registers. Off-diag weight 2, diag 1.
// C/D: col = lane&31, row = (reg&3) + 8*(reg>>2) + 4*(lane>>5).
__device__ __forceinline__ void dense_sweep32(const ushort* __restrict__ zhl,
                                              const float* __restrict__ v,
                                              short8_t afrag, const float4* u4,
                                              int ti, int tj0, int cnt, int c31,
                                              float& ax, float& ay, float& az, float& aw) {
    const ushort* bp0 = zhl + (size_t)c31 * 16;
    const float*  vp0 = v + c31;
    for (int t0 = 0; t0 < cnt; t0 += CH) {
        short8_t hh[CH], ll[CH];
        float    vv[CH];
        #pragma unroll
        for (int k = 0; k < CH; ++k) {
            int tk = t0 + k;
            int T  = tj0 + (tk < cnt ? tk : cnt - 1);     // clamped dup, unused
            hh[k] = *(const short8_t*)(bp0 + (size_t)T * 512);
            ll[k] = *(const short8_t*)(bp0 + (size_t)T * 512 + 8);
            vv[k] = vp0[T * 32];
        }
        int m = cnt - t0; if (m > CH) m = CH;
        #pragma unroll
        for (int k = 0; k < CH; ++k) {
            if (k < m) {
                float w = (tj0 + t0 + k == ti) ? 1.f : 2.f;
                f32x16 c = { 0.f, 0.f, 0.f, 0.f, 0.f, 0.f, 0.f, 0.f,
                             0.f, 0.f, 0.f, 0.f, 0.f, 0.f, 0.f, 0.f };
                c = __builtin_amdgcn_mfma_f32_32x32x16_bf16(afrag, hh[k], c, 0, 0, 0);
                c = __builtin_amdgcn_mfma_f32_32x32x16_bf16(afrag, ll[k], c, 0, 0, 0);
                #pragma unroll
                for (int q = 0; q < 4; ++q) {
                    float s0 = u4[q].x + vv[k], s1 = u4[q].y + vv[k];
                    float s2 = u4[q].z + vv[k], s3 = u4[q].w + vv[k];
                    float d0 = fmaf(c[4*q+0], -2.f, s0);
                    float d1 = fmaf(c[4*q+1], -2.f, s1);
                    float d2 = fmaf(c[4*q+2], -2.f, s2);
                    float d3 = fmaf(c[4*q+3], -2.f, s3);
                    ax = fmaf(w, __builtin_amdgcn_exp2f(-__builtin_amdgcn_sqrtf(__builtin_fabsf(d0))), ax);
                    ay = fmaf(w, __builtin_amdgcn_exp2f(-__builtin_amdgcn_sqrtf(__builtin_fabsf(d1))), ay);
                    az = fmaf(w, __builtin_amdgcn_exp2f(-__builtin_amdgcn_sqrtf(__builtin_fabsf(d2))), az);
                    aw = fmaf(w, __builtin_amdgcn_exp2f(-__builtin_amdgcn_sqrtf(__builtin_fabsf(d3))), aw);
                }
            }
        }
    }
}

// ---- kernel 2: sparse || dense 32x32 triangle; bucketed atomic finalize ----
__global__ __launch_bounds__(256) void fused_kernel(
        const ushort* __restrict__ zhl, const float* __restrict__ u,
        const float* __restrict__ v, const ushort* __restrict__ zb16,
        const int* __restrict__ ei, const int* __restrict__ ej, int ne,
        const float* __restrict__ alpha, char* __restrict__ buckets,
        float* __restrict__ out) {
    __shared__ float red[4];
    __shared__ unsigned composeFlag;
    int tid = threadIdx.x, bx = blockIdx.x;
    float s;

    if (bx < NSBLK) {
        // ---- sparse positive-edge term: 8-edge chunks, 16 gathers in flight ----
        const uint4* zb = (const uint4*)zb16;
        const int4* ei4 = (const int4*)ei;
        const int4* ej4 = (const int4*)ej;
        float acc = 0.f;
        int nchunk = ne >> 3;
        int stride = NSBLK * 256;
        int c = bx * 256 + tid;
        if (c < nchunk) {
            int4 ia0 = ei4[2*c], ia1 = ei4[2*c+1];
            int4 ib0 = ej4[2*c], ib1 = ej4[2*c+1];
            while (true) {
                int cn = c + stride;
                bool more = cn < nchunk;
                int4 na0, na1, nb0, nb1;
                if (more) {
                    na0 = ei4[2*cn]; na1 = ei4[2*cn+1];
                    nb0 = ej4[2*cn]; nb1 = ej4[2*cn+1];
                }
                acc += edge_dist8(zb, ia0, ia1, ib0, ib1);
                if (!more) break;
                ia0 = na0; ia1 = na1; ib0 = nb0; ib1 = nb1; c = cn;
            }
        }
        // tail (ne % 8)
        for (int e = (nchunk << 3) + bx * 256 + tid; e < ne; e += stride) {
            uint4 ua = zb[ei[e]];
            uint4 ub = zb[ej[e]];
            float fa[8], fb[8];
            UNPACK8(ua, fa);
            UNPACK8(ub, fb);
            float s2 = 0.f;
            #pragma unroll
            for (int k = 0; k < 8; ++k) {
                float d = fa[k] - fb[k] + EPSF;
                s2 = fmaf(d, d, s2);
            }
            acc += __builtin_amdgcn_sqrtf(s2);
        }
        s = block_reduce_f(acc, red);
    } else {
        // ---- dense term (upper-triangle 32x32 tiles, row-paired) ----
        int dbx  = bx - NSBLK;
        int wave = tid >> 6, lane = tid & 63;
        int g = lane >> 5, c31 = lane & 31;

        int p  = dbx >> 3;                       // row-pair index [0,128)
        int wv = (dbx & 7) * 4 + wave;           // wave within pair [0,32)
        int k0 = (wv * 257) / NWPP;
        int k1 = ((wv + 1) * 257) / NWPP;
        int n1 = NT2 - p;                        // tiles in row ti = p

        float ax = 0.f, ay = 0.f, az = 0.f, aw = 0.f;

        int eA = k1 < n1 ? k1 : n1;
        if (k0 < eA) {
            int ti = p;
            short8_t afrag = *(const short8_t*)(zhl + (size_t)(ti * 32 + c31) * 16 + g * 8);
            float4 u4[4];
            #pragma unroll
            for (int q = 0; q < 4; ++q) u4[q] = *(const float4*)(u + ti * 32 + 8 * q + 4 * g);
            dense_sweep32(zhl, v, afrag, u4, ti, p + k0, eA - k0, c31, ax, ay, az, aw);
        }
        int sB = k0 > n1 ? k0 : n1;
        if (sB < k1) {
            int ti = (NT2 - 1) - p;
            short8_t afrag = *(const short8_t*)(zhl + (size_t)(ti * 32 + c31) * 16 + g * 8);
            float4 u4[4];
            #pragma unroll
            for (int q = 0; q < 4; ++q) u4[q] = *(const float4*)(u + ti * 32 + 8 * q + 4 * g);
            dense_sweep32(zhl, v, afrag, u4, ti, ti + (sB - n1), k1 - sB, c31, ax, ay, az, aw);
        }
        s = block_reduce_f((ax + ay) + (az + aw), red);
    }

    // ---- bucketed finalize: 80 buckets x 16 blocks, <=16-deep atomic chains ----
    double* dbuck = (double*)(buckets);
    double* sbuck = (double*)(buckets + 64 * 128);
    unsigned* gdone = (unsigned*)(buckets + 160 * 128);

    if (tid == 0) {
        int  sparse = (bx < NSBLK);
        int  sid = sparse ? (bx & 15) : ((bx - NSBLK) & 63);
        int  cid = sparse ? (64 + (bx >> 4)) : ((bx - NSBLK) >> 4);
        double* sumslot = sparse ? (double*)((char*)sbuck + sid * 128)
                                 : (double*)((char*)dbuck + sid * 128);
        (void)atomicAdd(sumslot, (double)s);
        __builtin_amdgcn_s_waitcnt(0);                 // sum add complete
        unsigned oc = atomicAdd((unsigned*)(buckets + (80 + cid) * 128), 1u);
        unsigned g = 0xFFFFu;
        if (oc == 15u) {
            __builtin_amdgcn_s_waitcnt(0);
            g = atomicAdd(gdone, 1u);
        }
        composeFlag = (g == 79u) ? 1u : 0u;
    }
    __syncthreads();

    if (composeFlag) {
        __shared__ double acc2[2];
        int lane = tid & 63, w = tid >> 6;
        double val = 0.0;
        if (w == 0) val = atomicAdd((double*)((char*)dbuck + lane * 128), 0.0);
        else if (w == 1 && lane < 16) val = atomicAdd((double*)((char*)sbuck + lane * 128), 0.0);
        #pragma unroll
        for (int off = 32; off > 0; off >>= 1) val += __shfl_down(val, off, 64);
        if (w == 0 && lane == 0) acc2[0] = val;
        if (w == 1 && lane == 0) acc2[1] = val;
        __syncthreads();
        if (tid == 0) {
            double Dsum = acc2[0], Ssum = acc2[1];
            double trace = (double)S * exp(-sqrt(8.0) * (double)EPSF);
            double offdiag = Dsum - trace;
            double a = (double)alpha[0];
            double z_pdist2 = (double)ne * a - Ssum;
            double z_pdist1 = exp(a) * 0.5 * 7.3890560989306495 * offdiag;
            out[0] = (float)(z_pdist2 - z_pdist1);
        }
    }
}

extern "C" void kernel_launch(void* const* d_in, const int* in_sizes, int n_in,
                              void* d_out, int out_size, void* d_ws, size_t ws_size,
                              hipStream_t stream) {
    const float* latent_Z = (const float*)d_in[0];
    const float* alpha    = (const float*)d_in[1];
    const int*   sidx     = (const int*)d_in[2];
    const int*   ei       = (const int*)d_in[3];
    const int*   ej       = (const int*)d_in[4];
    int ne = in_sizes[3];
    float* out = (float*)d_out;
    char*  ws  = (char*)d_ws;

    ushort* zhl   = (ushort*)(ws + ZHL_OFF);
    float*  u     = (float*)(ws + U_OFF);
    float*  v     = (float*)(ws + V_OFF);
    ushort* zb16  = (ushort*)(ws + ZB_OFF);
    char*   bk    = ws + BK_OFF;

    gather_kernel<<<(NNODES + 255) / 256, 256, 0, stream>>>(latent_Z, sidx,
                                                            zhl, u, v, zb16, bk);
    fused_kernel<<<NSBLK + NDBLK, 256, 0, stream>>>(zhl, u, v, zb16, ei, ej, ne,
                                                    alpha, bk, out);
}